// Round 21
// baseline (446.936 us; speedup 1.0000x reference)
//
#include <hip/hip_runtime.h>

// AdaTTSp on MI355X. B=32768, T=8, E=2, NE=16, D=H=128, L=2.
// Round 21 = r18 verbatim (best: 269.7us; r19/r20 experiments both regressed
// and are reverted) + ONE change: kmix's 16-expert mix loop batches eo reads
// 8-deep (evv[8] array -> 8 loads in flight) instead of the serial
// load->cvt->fma chain (r19 counters: kmix 75us, 39% HBM, VGPR 56, Occ 26%
// -> latency-bound on the 128MB eo stream).

typedef float f32x4 __attribute__((ext_vector_type(4)));
typedef _Float16 f16;
typedef f16 f16x8 __attribute__((ext_vector_type(8)));
typedef f16 f16x4 __attribute__((ext_vector_type(4)));

#define MFMA(a, b, c) __builtin_amdgcn_mfma_f32_16x16x32_f16(a, b, c, 0, 0, 0)
#define LOSC (1.0f / 2048.0f)
#define AS1 __attribute__((address_space(1)))
#define AS3 __attribute__((address_space(3)))

__device__ __forceinline__ void split2h(float f, f16& h, f16& l) {
  h = (f16)f;
  l = (f16)((f - (float)h) * 2048.0f);
}

// ---------------------------------------------------------------------------
// Merged prep (r18): blocks [0,16384) cast x0 f32->fp16; blocks [16384,16912)
// transform weights (w1T/w2T single-fp16 fragments; gwT hi/lo pair).
__global__ __launch_bounds__(256) void kprep(
    const float* __restrict__ x0, const float* __restrict__ w1,
    const float* __restrict__ w2, const float* __restrict__ gw,
    f16* __restrict__ x0h, f16* __restrict__ w1T, f16* __restrict__ w2T,
    f16* __restrict__ gwT) {
  int bid = blockIdx.x;
  int tid = threadIdx.x;
  if (bid < 16384) {
    size_t i = ((size_t)bid * 256 + tid) * 8;
    f32x4 f0 = *(const f32x4*)(x0 + i);
    f32x4 f1 = *(const f32x4*)(x0 + i + 4);
    f16x8 v;
#pragma unroll
    for (int z = 0; z < 4; ++z) {
      v[z] = (f16)f0[z];
      v[4 + z] = (f16)f1[z];
    }
    *(f16x8*)(x0h + i) = v;
    return;
  }
  int idx = (bid - 16384) * 256 + tid;
  if (idx < 131072) {
    const float* src = (idx < 65536) ? w1 : w2;
    f16* dst = (idx < 65536) ? w1T : w2T;
    int i = idx & 65535;
    int lane = i & 63;
    int it = (i >> 6) & 7;
    int ks = (i >> 9) & 3;
    int q = i >> 11;
    int g = lane >> 4, le = lane & 15;
    f16x8 vh;
#pragma unroll
    for (int j = 0; j < 8; ++j)
      vh[j] = (f16)src[((size_t)q * 128 + (32 * ks + 8 * g + j)) * 128 + 16 * it + le];
    *(f16x8*)(dst + (size_t)i * 8) = vh;
  } else {
    int i = idx - 131072;  // 0..4095
    int lane = i & 63;
    int ks = (i >> 6) & 3;
    int q = (i >> 8) & 15;
    int g = lane >> 4, le = lane & 15;
    f16x8 vh, vl;
#pragma unroll
    for (int j = 0; j < 8; ++j) {
      float f = gw[((size_t)q * 128 + (32 * ks + 8 * g + j)) * 16 + le];
      f16 h, l;
      split2h(f, h, l);
      vh[j] = h;
      vl[j] = l;
    }
    *(f16x8*)(gwT + (size_t)i * 8) = vh;
    *(f16x8*)(gwT + 32768 + (size_t)i * 8) = vl;
  }
}

// ---------------------------------------------------------------------------
// Expert kernel (r18 verbatim). grid = 512 blocks; 256 thr (4 waves).
// Wave = (jh = wave&1: 32-row half, oh = wave>>1: 64-oc half).
__global__ __launch_bounds__(256, 2) void kexp(
    const f16* __restrict__ xs, const f16* __restrict__ w1T,
    const f16* __restrict__ w2T, const float* __restrict__ b1,
    const float* __restrict__ b2, f16* __restrict__ eo, int layer) {
  __shared__ f16 sX[2][8192];  // 64 x 128, dbuf (32KB)
  __shared__ f16 sH[8192];     // 16KB
  __shared__ f16 sEO[8192];    // 16KB
  const int tid = threadIdx.x;
  const int lane = tid & 63;
  const int wave = tid >> 6;
  const int jh = wave & 1, oh = wave >> 1;
  const int g = lane >> 4, le = lane & 15;
  const int e = blockIdx.x & 15;
  const int r0 = (blockIdx.x >> 4) * 1024;
  const int te = e >> 1;
  const int lx = layer * 16 + e;

  f16x8 w1r[4][4], w2r[4][4];
#pragma unroll
  for (int it = 0; it < 4; ++it)
#pragma unroll
    for (int ks = 0; ks < 4; ++ks) {
      size_t fb = ((size_t)((lx * 4 + ks) * 8 + 4 * oh + it) * 64 + lane) * 8;
      w1r[it][ks] = *(const f16x8*)(w1T + fb);
      w2r[it][ks] = *(const f16x8*)(w2T + fb);
    }
  f32x4 b1v[4], b2v[4];
#pragma unroll
  for (int it = 0; it < 4; ++it) {
    b1v[it] = *(const f32x4*)(b1 + lx * 128 + 64 * oh + 16 * it + 4 * g);
    b2v[it] = *(const f32x4*)(b2 + lx * 128 + 64 * oh + 16 * it + 4 * g);
  }

  auto stage_gl = [&](int buf, int tile) {
#pragma unroll
    for (int i = 0; i < 4; ++i) {
      int row = 16 * wave + 4 * i + (lane >> 4);
      int gc = lane & 15;
      const f16* src = xs + ((size_t)(r0 + tile * 64 + row) * 8 + te) * 128 +
                       (gc ^ (row & 7)) * 8;
      f16* dst = &sX[buf][(16 * wave + 4 * i) * 128];
      __builtin_amdgcn_global_load_lds((const AS1 void*)src, (AS3 void*)dst,
                                       16, 0, 0);
    }
  };
  auto eo_flush = [&](int tile) {
#pragma unroll
    for (int i = 0; i < 4; ++i) {
      int slot = i * 256 + tid;
      int row = slot >> 4, c = slot & 15;
      f16x8 v = *(const f16x8*)(&sEO[row * 128 + 8 * (c ^ (row & 7))]);
      *(f16x8*)(eo + ((size_t)e * 32768 + (r0 + tile * 64 + row)) * 128 + 8 * c) = v;
    }
  };

  stage_gl(0, 0);
  __syncthreads();

  for (int tile = 0; tile < 16; ++tile) {
    const int b = tile & 1;
    if (tile < 15) stage_gl(b ^ 1, tile + 1);
    if (tile > 0) eo_flush(tile - 1);
    {
      f32x4 a[4][2];
#pragma unroll
      for (int it = 0; it < 4; ++it)
#pragma unroll
        for (int j2 = 0; j2 < 2; ++j2) a[it][j2] = f32x4{0.f, 0.f, 0.f, 0.f};
#pragma unroll
      for (int ks = 0; ks < 4; ++ks)
#pragma unroll
        for (int j2 = 0; j2 < 2; ++j2) {
          int brow = 32 * jh + 16 * j2 + le;
          f16x8 bf = *(const f16x8*)(&sX[b][brow * 128 + 8 * ((4 * ks + g) ^ (brow & 7))]);
#pragma unroll
          for (int it = 0; it < 4; ++it)
            a[it][j2] = MFMA(w1r[it][ks], bf, a[it][j2]);
        }
#pragma unroll
      for (int it = 0; it < 4; ++it)
#pragma unroll
        for (int j2 = 0; j2 < 2; ++j2) {
          int brow = 32 * jh + 16 * j2 + le;
          f16x4 hv;
#pragma unroll
          for (int r = 0; r < 4; ++r)
            hv[r] = (f16)fmaxf(a[it][j2][r] + b1v[it][r], 0.f);
          int gran = 8 * oh + 2 * it + (g >> 1);
          *(f16x4*)(&sH[brow * 128 + 8 * (gran ^ (brow & 7)) + 4 * (g & 1)]) = hv;
        }
    }
    __syncthreads();
    {
      f32x4 a[4][2];
#pragma unroll
      for (int it = 0; it < 4; ++it)
#pragma unroll
        for (int j2 = 0; j2 < 2; ++j2) a[it][j2] = f32x4{0.f, 0.f, 0.f, 0.f};
#pragma unroll
      for (int ks = 0; ks < 4; ++ks)
#pragma unroll
        for (int j2 = 0; j2 < 2; ++j2) {
          int brow = 32 * jh + 16 * j2 + le;
          f16x8 bf = *(const f16x8*)(&sH[brow * 128 + 8 * ((4 * ks + g) ^ (brow & 7))]);
#pragma unroll
          for (int it = 0; it < 4; ++it)
            a[it][j2] = MFMA(w2r[it][ks], bf, a[it][j2]);
        }
#pragma unroll
      for (int it = 0; it < 4; ++it)
#pragma unroll
        for (int j2 = 0; j2 < 2; ++j2) {
          int brow = 32 * jh + 16 * j2 + le;
          f16x4 ev;
#pragma unroll
          for (int r = 0; r < 4; ++r)
            ev[r] = (f16)fmaxf(a[it][j2][r] + b2v[it][r], 0.f);
          int gran = 8 * oh + 2 * it + (g >> 1);
          *(f16x4*)(&sEO[brow * 128 + 8 * (gran ^ (brow & 7)) + 4 * (g & 1)]) = ev;
        }
    }
#pragma unroll
    for (int it = 0; it < 4; ++it)
#pragma unroll
      for (int ks = 0; ks < 4; ++ks) {
        asm volatile("" : "+v"(w1r[it][ks]));
        asm volatile("" : "+v"(w2r[it][ks]));
      }
    __syncthreads();
  }
  eo_flush(15);
}

// ---------------------------------------------------------------------------
// Gate + mix kernel. grid = 1024 blocks (32 rows), 512 thr.
// CHANGED vs r18: mix loop processes experts in two half-batches of 8 with
// all 8 eo loads issued before any accumulation (8-deep MLP).
__global__ __launch_bounds__(512, 4) void kmix(
    const f16* __restrict__ xs, const f16* __restrict__ gwT,
    const float* __restrict__ gb, const float* __restrict__ sw,
    const f16* __restrict__ eo, f16* __restrict__ x1out,
    float* __restrict__ fout, int layer) {
  __shared__ float sG[8 * 16 * 32];  // [t][e][row32] 16KB
  const int tid = threadIdx.x;
  const int lane = tid & 63;
  const int t = tid >> 6;
  const int g = lane >> 4, le = lane & 15;
  const int r0 = blockIdx.x * 32;
  const int lt = layer * 8 + t;

  {  // ---- gates (r18 verbatim) ----
    f32x4 l1[2], l2[2];
#pragma unroll
    for (int j = 0; j < 2; ++j) {
      l1[j] = f32x4{0.f, 0.f, 0.f, 0.f};
      l2[j] = f32x4{0.f, 0.f, 0.f, 0.f};
    }
#pragma unroll
    for (int ks = 0; ks < 4; ++ks) {
      size_t fb = ((size_t)(lt * 4 + ks) * 64 + lane) * 8;
      f16x8 ah = *(const f16x8*)(gwT + fb);
      f16x8 al = *(const f16x8*)(gwT + 32768 + fb);
#pragma unroll
      for (int j = 0; j < 2; ++j) {
        f16x8 bf = *(const f16x8*)(xs + ((size_t)(r0 + 16 * j + le) * 8 + t) * 128 +
                                   32 * ks + 8 * g);
        l1[j] = MFMA(ah, bf, l1[j]);
        l2[j] = MFMA(al, bf, l2[j]);
      }
    }
#pragma unroll
    for (int j = 0; j < 2; ++j) {
      float zb[4];
#pragma unroll
      for (int r = 0; r < 4; ++r)
        zb[r] = l1[j][r] + l2[j][r] * LOSC + gb[lt * 16 + 4 * g + r];
      float m4 = fmaxf(fmaxf(zb[0], zb[1]), fmaxf(zb[2], zb[3]));
      m4 = fmaxf(m4, __shfl_xor(m4, 16, 64));
      m4 = fmaxf(m4, __shfl_xor(m4, 32, 64));
      float p4[4], s4 = 0.f;
#pragma unroll
      for (int r = 0; r < 4; ++r) {
        p4[r] = __expf(zb[r] - m4);
        s4 += p4[r];
      }
      s4 += __shfl_xor(s4, 16, 64);
      s4 += __shfl_xor(s4, 32, 64);
      float inv = 1.f / s4;
#pragma unroll
      for (int r = 0; r < 4; ++r)
        sG[(t * 16 + 4 * g + r) * 32 + 16 * j + le] = p4[r] * inv;
    }
  }
  __syncthreads();

  // ---- mix: two half-batches of 8 experts, loads issued up front ----
  const int lrow = tid >> 4;
  const int grow = r0 + lrow;
  const int cq = (tid & 15) * 8;
  f32x4 am[8][2];
#pragma unroll
  for (int tt = 0; tt < 8; ++tt)
#pragma unroll
    for (int k = 0; k < 2; ++k) am[tt][k] = f32x4{0.f, 0.f, 0.f, 0.f};

#pragma unroll
  for (int half = 0; half < 2; ++half) {
    f16x8 evv[8];
#pragma unroll
    for (int q = 0; q < 8; ++q) {
      int ee = half * 8 + q;
      evv[q] = *(const f16x8*)(eo + ((size_t)ee * 32768 + grow) * 128 + cq);
    }
#pragma unroll
    for (int q = 0; q < 8; ++q) {
      int ee = half * 8 + q;
      const int tte = ee >> 1, eh = ee & 1;
      float evf[8];
#pragma unroll
      for (int z = 0; z < 8; ++z) evf[z] = (float)evv[q][z];
      float ssew = sw[(layer * 8 + tte) * 2 + eh];
#pragma unroll
      for (int tt = 0; tt < 8; ++tt) {
        float coef = sG[(tt * 16 + ee) * 32 + lrow] + (tt == tte ? ssew : 0.f);
#pragma unroll
        for (int z = 0; z < 8; ++z)
          am[tt][z >> 2][z & 3] = fmaf(coef, evf[z], am[tt][z >> 2][z & 3]);
      }
    }
  }
#pragma unroll
  for (int tt = 0; tt < 8; ++tt) {
    size_t off = ((size_t)grow * 8 + tt) * 128 + cq;
    if (layer == 0) {
      f16x8 hv;
#pragma unroll
      for (int z = 0; z < 8; ++z) hv[z] = (f16)am[tt][z >> 2][z & 3];
      *(f16x8*)(x1out + off) = hv;
    } else {
      *(f32x4*)(fout + off) = am[tt][0];
      *(f32x4*)(fout + off + 4) = am[tt][1];
    }
  }
}

// ---------------------------------------------------------------------------
extern "C" void kernel_launch(void* const* d_in, const int* in_sizes, int n_in,
                              void* d_out, int out_size, void* d_ws, size_t ws_size,
                              hipStream_t stream) {
  const float* x0 = (const float*)d_in[0];
  const float* w1 = (const float*)d_in[1];
  const float* b1 = (const float*)d_in[2];
  const float* w2 = (const float*)d_in[3];
  const float* b2 = (const float*)d_in[4];
  const float* gw = (const float*)d_in[5];
  const float* gb = (const float*)d_in[6];
  const float* sw = (const float*)d_in[7];

  // ws bytes: w1T [0,1MB) | w2T [1MB,2MB) | gwT pair [2MB,+128KB)
  // | x0h fp16 [4MB,+64MB) | x1h fp16 [68MB,+64MB) | eo fp16 [132MB,+128MB)
  f16* w1T = (f16*)d_ws;
  f16* w2T = (f16*)((char*)d_ws + 1048576);
  f16* gwT = (f16*)((char*)d_ws + 2097152);
  f16* x0h = (f16*)((char*)d_ws + 4194304);
  f16* x1h = (f16*)((char*)d_ws + 71303168);
  f16* eo = (f16*)((char*)d_ws + 138412032);
  float* out = (float*)d_out;

  kprep<<<16912, 256, 0, stream>>>(x0, w1, w2, gw, x0h, w1T, w2T, gwT);

  kexp<<<512, 256, 0, stream>>>(x0h, w1T, w2T, b1, b2, eo, 0);
  kmix<<<1024, 512, 0, stream>>>(x0h, gwT, gb, sw, eo, x1h, nullptr, 0);
  kexp<<<512, 256, 0, stream>>>(x1h, w1T, w2T, b1, b2, eo, 1);
  kmix<<<1024, 512, 0, stream>>>(x1h, gwT, gb, sw, eo, nullptr, out, 1);
}

// Round 22
// 269.756 us; speedup vs baseline: 1.6568x; 1.6568x over previous
//
#include <hip/hip_runtime.h>

// AdaTTSp on MI355X. B=32768, T=8, E=2, NE=16, D=H=128, L=2.
// Round 22 = r18 verbatim (best measured: 269.7us). r19 (kexp 1-barrier
// pipeline + XCD swizzle + direct stores), r20 (gate precompute in kprep),
// r21 (kmix 8-deep eo batching -> 3.3x FETCH, L2/L3 thrash) ALL regressed
// and are reverted. This locks in the best-known configuration:
//  - kprep: merged x0 cast + weight fragment transforms
//  - kexp: expert-major, weights resident (4-it waves, 128 VGPR),
//    global_load_lds DMA staging (src-swizzled, linear LDS dest),
//    2 barriers/tile, sEO-buffered coalesced e-major eo flush
//  - kmix: MFMA gates (hi/lo gw) + shfl softmax + serial-stream mix
//    (serial loop preserves L3 locality on the eo stream)
// Numerics: fp16 weights/activations, f32 accum; absmax 9.77e-4 (4.2x
// headroom under the 4.08e-3 threshold).

typedef float f32x4 __attribute__((ext_vector_type(4)));
typedef _Float16 f16;
typedef f16 f16x8 __attribute__((ext_vector_type(8)));
typedef f16 f16x4 __attribute__((ext_vector_type(4)));

#define MFMA(a, b, c) __builtin_amdgcn_mfma_f32_16x16x32_f16(a, b, c, 0, 0, 0)
#define LOSC (1.0f / 2048.0f)
#define AS1 __attribute__((address_space(1)))
#define AS3 __attribute__((address_space(3)))

__device__ __forceinline__ void split2h(float f, f16& h, f16& l) {
  h = (f16)f;
  l = (f16)((f - (float)h) * 2048.0f);
}

// ---------------------------------------------------------------------------
// Merged prep: blocks [0,16384) cast x0 f32->fp16; blocks [16384,16912)
// transform weights (w1T/w2T single-fp16 fragments; gwT hi/lo pair).
__global__ __launch_bounds__(256) void kprep(
    const float* __restrict__ x0, const float* __restrict__ w1,
    const float* __restrict__ w2, const float* __restrict__ gw,
    f16* __restrict__ x0h, f16* __restrict__ w1T, f16* __restrict__ w2T,
    f16* __restrict__ gwT) {
  int bid = blockIdx.x;
  int tid = threadIdx.x;
  if (bid < 16384) {
    size_t i = ((size_t)bid * 256 + tid) * 8;
    f32x4 f0 = *(const f32x4*)(x0 + i);
    f32x4 f1 = *(const f32x4*)(x0 + i + 4);
    f16x8 v;
#pragma unroll
    for (int z = 0; z < 4; ++z) {
      v[z] = (f16)f0[z];
      v[4 + z] = (f16)f1[z];
    }
    *(f16x8*)(x0h + i) = v;
    return;
  }
  int idx = (bid - 16384) * 256 + tid;
  if (idx < 131072) {
    const float* src = (idx < 65536) ? w1 : w2;
    f16* dst = (idx < 65536) ? w1T : w2T;
    int i = idx & 65535;
    int lane = i & 63;
    int it = (i >> 6) & 7;
    int ks = (i >> 9) & 3;
    int q = i >> 11;
    int g = lane >> 4, le = lane & 15;
    f16x8 vh;
#pragma unroll
    for (int j = 0; j < 8; ++j)
      vh[j] = (f16)src[((size_t)q * 128 + (32 * ks + 8 * g + j)) * 128 + 16 * it + le];
    *(f16x8*)(dst + (size_t)i * 8) = vh;
  } else {
    int i = idx - 131072;  // 0..4095
    int lane = i & 63;
    int ks = (i >> 6) & 3;
    int q = (i >> 8) & 15;
    int g = lane >> 4, le = lane & 15;
    f16x8 vh, vl;
#pragma unroll
    for (int j = 0; j < 8; ++j) {
      float f = gw[((size_t)q * 128 + (32 * ks + 8 * g + j)) * 16 + le];
      f16 h, l;
      split2h(f, h, l);
      vh[j] = h;
      vl[j] = l;
    }
    *(f16x8*)(gwT + (size_t)i * 8) = vh;
    *(f16x8*)(gwT + 32768 + (size_t)i * 8) = vl;
  }
}

// ---------------------------------------------------------------------------
// Expert kernel. grid = 32 rowblocks(1024) x 16 experts = 512 blocks;
// 256 thr (4 waves), 2 blocks/CU. 16 tiles x 64 rows.
// Wave = (jh = wave&1: 32-row half, oh = wave>>1: 64-oc half).
// Weights in regs: w{1,2}r[it 0..3][ks] = 128 VGPR; b-frag read feeds 4 MFMA.
// Staging: global_load_lds, swizzle in the global source.
__global__ __launch_bounds__(256, 2) void kexp(
    const f16* __restrict__ xs, const f16* __restrict__ w1T,
    const f16* __restrict__ w2T, const float* __restrict__ b1,
    const float* __restrict__ b2, f16* __restrict__ eo, int layer) {
  __shared__ f16 sX[2][8192];  // 64 x 128, dbuf (32KB)
  __shared__ f16 sH[8192];     // 16KB
  __shared__ f16 sEO[8192];    // 16KB
  const int tid = threadIdx.x;
  const int lane = tid & 63;
  const int wave = tid >> 6;
  const int jh = wave & 1, oh = wave >> 1;
  const int g = lane >> 4, le = lane & 15;
  const int e = blockIdx.x & 15;
  const int r0 = (blockIdx.x >> 4) * 1024;
  const int te = e >> 1;
  const int lx = layer * 16 + e;

  f16x8 w1r[4][4], w2r[4][4];
#pragma unroll
  for (int it = 0; it < 4; ++it)
#pragma unroll
    for (int ks = 0; ks < 4; ++ks) {
      size_t fb = ((size_t)((lx * 4 + ks) * 8 + 4 * oh + it) * 64 + lane) * 8;
      w1r[it][ks] = *(const f16x8*)(w1T + fb);
      w2r[it][ks] = *(const f16x8*)(w2T + fb);
    }
  f32x4 b1v[4], b2v[4];
#pragma unroll
  for (int it = 0; it < 4; ++it) {
    b1v[it] = *(const f32x4*)(b1 + lx * 128 + 64 * oh + 16 * it + 4 * g);
    b2v[it] = *(const f32x4*)(b2 + lx * 128 + 64 * oh + 16 * it + 4 * g);
  }

  auto stage_gl = [&](int buf, int tile) {
#pragma unroll
    for (int i = 0; i < 4; ++i) {
      int row = 16 * wave + 4 * i + (lane >> 4);
      int gc = lane & 15;
      const f16* src = xs + ((size_t)(r0 + tile * 64 + row) * 8 + te) * 128 +
                       (gc ^ (row & 7)) * 8;
      f16* dst = &sX[buf][(16 * wave + 4 * i) * 128];
      __builtin_amdgcn_global_load_lds((const AS1 void*)src, (AS3 void*)dst,
                                       16, 0, 0);
    }
  };
  auto eo_flush = [&](int tile) {
#pragma unroll
    for (int i = 0; i < 4; ++i) {
      int slot = i * 256 + tid;
      int row = slot >> 4, c = slot & 15;
      f16x8 v = *(const f16x8*)(&sEO[row * 128 + 8 * (c ^ (row & 7))]);
      *(f16x8*)(eo + ((size_t)e * 32768 + (r0 + tile * 64 + row)) * 128 + 8 * c) = v;
    }
  };

  stage_gl(0, 0);
  __syncthreads();

  for (int tile = 0; tile < 16; ++tile) {
    const int b = tile & 1;
    if (tile < 15) stage_gl(b ^ 1, tile + 1);
    if (tile > 0) eo_flush(tile - 1);
    {
      f32x4 a[4][2];
#pragma unroll
      for (int it = 0; it < 4; ++it)
#pragma unroll
        for (int j2 = 0; j2 < 2; ++j2) a[it][j2] = f32x4{0.f, 0.f, 0.f, 0.f};
#pragma unroll
      for (int ks = 0; ks < 4; ++ks)
#pragma unroll
        for (int j2 = 0; j2 < 2; ++j2) {
          int brow = 32 * jh + 16 * j2 + le;
          f16x8 bf = *(const f16x8*)(&sX[b][brow * 128 + 8 * ((4 * ks + g) ^ (brow & 7))]);
#pragma unroll
          for (int it = 0; it < 4; ++it)
            a[it][j2] = MFMA(w1r[it][ks], bf, a[it][j2]);
        }
#pragma unroll
      for (int it = 0; it < 4; ++it)
#pragma unroll
        for (int j2 = 0; j2 < 2; ++j2) {
          int brow = 32 * jh + 16 * j2 + le;
          f16x4 hv;
#pragma unroll
          for (int r = 0; r < 4; ++r)
            hv[r] = (f16)fmaxf(a[it][j2][r] + b1v[it][r], 0.f);
          int gran = 8 * oh + 2 * it + (g >> 1);
          *(f16x4*)(&sH[brow * 128 + 8 * (gran ^ (brow & 7)) + 4 * (g & 1)]) = hv;
        }
    }
    __syncthreads();
    {
      f32x4 a[4][2];
#pragma unroll
      for (int it = 0; it < 4; ++it)
#pragma unroll
        for (int j2 = 0; j2 < 2; ++j2) a[it][j2] = f32x4{0.f, 0.f, 0.f, 0.f};
#pragma unroll
      for (int ks = 0; ks < 4; ++ks)
#pragma unroll
        for (int j2 = 0; j2 < 2; ++j2) {
          int brow = 32 * jh + 16 * j2 + le;
          f16x8 bf = *(const f16x8*)(&sH[brow * 128 + 8 * ((4 * ks + g) ^ (brow & 7))]);
#pragma unroll
          for (int it = 0; it < 4; ++it)
            a[it][j2] = MFMA(w2r[it][ks], bf, a[it][j2]);
        }
#pragma unroll
      for (int it = 0; it < 4; ++it)
#pragma unroll
        for (int j2 = 0; j2 < 2; ++j2) {
          int brow = 32 * jh + 16 * j2 + le;
          f16x4 ev;
#pragma unroll
          for (int r = 0; r < 4; ++r)
            ev[r] = (f16)fmaxf(a[it][j2][r] + b2v[it][r], 0.f);
          int gran = 8 * oh + 2 * it + (g >> 1);
          *(f16x4*)(&sEO[brow * 128 + 8 * (gran ^ (brow & 7)) + 4 * (g & 1)]) = ev;
        }
    }
#pragma unroll
    for (int it = 0; it < 4; ++it)
#pragma unroll
      for (int ks = 0; ks < 4; ++ks) {
        asm volatile("" : "+v"(w1r[it][ks]));
        asm volatile("" : "+v"(w2r[it][ks]));
      }
    __syncthreads();
  }
  eo_flush(15);
}

// ---------------------------------------------------------------------------
// Gate + mix kernel. grid = 1024 blocks (32 rows), 512 thr (8 waves).
// Serial mix loop (preserves L3 locality on the eo stream — r21's 8-deep
// batching tripled FETCH and regressed 2x).
__global__ __launch_bounds__(512, 4) void kmix(
    const f16* __restrict__ xs, const f16* __restrict__ gwT,
    const float* __restrict__ gb, const float* __restrict__ sw,
    const f16* __restrict__ eo, f16* __restrict__ x1out,
    float* __restrict__ fout, int layer) {
  __shared__ float sG[8 * 16 * 32];  // [t][e][row32] 16KB
  const int tid = threadIdx.x;
  const int lane = tid & 63;
  const int t = tid >> 6;
  const int g = lane >> 4, le = lane & 15;
  const int r0 = blockIdx.x * 32;
  const int lt = layer * 8 + t;

  {  // ---- gates ----
    f32x4 l1[2], l2[2];
#pragma unroll
    for (int j = 0; j < 2; ++j) {
      l1[j] = f32x4{0.f, 0.f, 0.f, 0.f};
      l2[j] = f32x4{0.f, 0.f, 0.f, 0.f};
    }
#pragma unroll
    for (int ks = 0; ks < 4; ++ks) {
      size_t fb = ((size_t)(lt * 4 + ks) * 64 + lane) * 8;
      f16x8 ah = *(const f16x8*)(gwT + fb);
      f16x8 al = *(const f16x8*)(gwT + 32768 + fb);
#pragma unroll
      for (int j = 0; j < 2; ++j) {
        f16x8 bf = *(const f16x8*)(xs + ((size_t)(r0 + 16 * j + le) * 8 + t) * 128 +
                                   32 * ks + 8 * g);
        l1[j] = MFMA(ah, bf, l1[j]);
        l2[j] = MFMA(al, bf, l2[j]);
      }
    }
#pragma unroll
    for (int j = 0; j < 2; ++j) {
      float zb[4];
#pragma unroll
      for (int r = 0; r < 4; ++r)
        zb[r] = l1[j][r] + l2[j][r] * LOSC + gb[lt * 16 + 4 * g + r];
      float m4 = fmaxf(fmaxf(zb[0], zb[1]), fmaxf(zb[2], zb[3]));
      m4 = fmaxf(m4, __shfl_xor(m4, 16, 64));
      m4 = fmaxf(m4, __shfl_xor(m4, 32, 64));
      float p4[4], s4 = 0.f;
#pragma unroll
      for (int r = 0; r < 4; ++r) {
        p4[r] = __expf(zb[r] - m4);
        s4 += p4[r];
      }
      s4 += __shfl_xor(s4, 16, 64);
      s4 += __shfl_xor(s4, 32, 64);
      float inv = 1.f / s4;
#pragma unroll
      for (int r = 0; r < 4; ++r)
        sG[(t * 16 + 4 * g + r) * 32 + 16 * j + le] = p4[r] * inv;
    }
  }
  __syncthreads();

  // ---- mix ----
  const int lrow = tid >> 4;
  const int grow = r0 + lrow;
  const int cq = (tid & 15) * 8;
  f32x4 am[8][2];
#pragma unroll
  for (int tt = 0; tt < 8; ++tt)
#pragma unroll
    for (int k = 0; k < 2; ++k) am[tt][k] = f32x4{0.f, 0.f, 0.f, 0.f};

  for (int ee = 0; ee < 16; ++ee) {
    const int tte = ee >> 1, eh = ee & 1;
    f16x8 ev = *(const f16x8*)(eo + ((size_t)ee * 32768 + grow) * 128 + cq);
    float evf[8];
#pragma unroll
    for (int z = 0; z < 8; ++z) evf[z] = (float)ev[z];
    float ssew = sw[(layer * 8 + tte) * 2 + eh];
#pragma unroll
    for (int tt = 0; tt < 8; ++tt) {
      float coef = sG[(tt * 16 + ee) * 32 + lrow] + (tt == tte ? ssew : 0.f);
#pragma unroll
      for (int z = 0; z < 8; ++z)
        am[tt][z >> 2][z & 3] = fmaf(coef, evf[z], am[tt][z >> 2][z & 3]);
    }
  }
#pragma unroll
  for (int tt = 0; tt < 8; ++tt) {
    size_t off = ((size_t)grow * 8 + tt) * 128 + cq;
    if (layer == 0) {
      f16x8 hv;
#pragma unroll
      for (int z = 0; z < 8; ++z) hv[z] = (f16)am[tt][z >> 2][z & 3];
      *(f16x8*)(x1out + off) = hv;
    } else {
      *(f32x4*)(fout + off) = am[tt][0];
      *(f32x4*)(fout + off + 4) = am[tt][1];
    }
  }
}

// ---------------------------------------------------------------------------
extern "C" void kernel_launch(void* const* d_in, const int* in_sizes, int n_in,
                              void* d_out, int out_size, void* d_ws, size_t ws_size,
                              hipStream_t stream) {
  const float* x0 = (const float*)d_in[0];
  const float* w1 = (const float*)d_in[1];
  const float* b1 = (const float*)d_in[2];
  const float* w2 = (const float*)d_in[3];
  const float* b2 = (const float*)d_in[4];
  const float* gw = (const float*)d_in[5];
  const float* gb = (const float*)d_in[6];
  const float* sw = (const float*)d_in[7];

  // ws bytes: w1T [0,1MB) | w2T [1MB,2MB) | gwT pair [2MB,+128KB)
  // | x0h fp16 [4MB,+64MB) | x1h fp16 [68MB,+64MB) | eo fp16 [132MB,+128MB)
  f16* w1T = (f16*)d_ws;
  f16* w2T = (f16*)((char*)d_ws + 1048576);
  f16* gwT = (f16*)((char*)d_ws + 2097152);
  f16* x0h = (f16*)((char*)d_ws + 4194304);
  f16* x1h = (f16*)((char*)d_ws + 71303168);
  f16* eo = (f16*)((char*)d_ws + 138412032);
  float* out = (float*)d_out;

  kprep<<<16912, 256, 0, stream>>>(x0, w1, w2, gw, x0h, w1T, w2T, gwT);

  kexp<<<512, 256, 0, stream>>>(x0h, w1T, w2T, b1, b2, eo, 0);
  kmix<<<1024, 512, 0, stream>>>(x0h, gwT, gb, sw, eo, x1h, nullptr, 0);
  kexp<<<512, 256, 0, stream>>>(x1h, w1T, w2T, b1, b2, eo, 1);
  kmix<<<1024, 512, 0, stream>>>(x1h, gwT, gb, sw, eo, nullptr, out, 1);
}